// Round 1
// baseline (78.254 us; speedup 1.0000x reference)
//
#include <hip/hip_runtime.h>
#include <hip/hip_bf16.h>

// Problem shape (fixed by reference setup_inputs):
//   bert_emb:    [B=4, Lp=256, D=768] fp32
//   pieces2word: [B=4, Lw=200, Lp=256] int32 (0/1)
//   out:         [B=4, Lw=200, D=768] fp32
// out[b,w,d] = max over {p : mask[b,w,p]!=0} of emb[b,p,d], else global min(emb).

#define B_  4
#define LP_ 256
#define LW_ 200
#define D_  768
#define D4_ (D_ / 4)   // 192 float4 per row

// ---- sortable encoding for fp32 so unsigned atomicMin == float min ----
__device__ __forceinline__ unsigned int enc_f32(float f) {
    unsigned int b = __float_as_uint(f);
    return (b & 0x80000000u) ? ~b : (b | 0x80000000u);
}
__device__ __forceinline__ float dec_f32(unsigned int u) {
    unsigned int b = (u & 0x80000000u) ? (u & 0x7FFFFFFFu) : ~u;
    return __uint_as_float(b);
}

__global__ void init_ws(unsigned int* ws) {
    if (threadIdx.x == 0) ws[0] = 0xFFFFFFFFu;  // encodes "+max", identity for min
}

// Global min over all of bert_emb (786432 floats), float4 grid-stride.
__global__ void min_reduce(const float4* __restrict__ x, int n4, unsigned int* ws) {
    float m = __uint_as_float(0x7F800000u);  // +inf
    for (int i = blockIdx.x * blockDim.x + threadIdx.x; i < n4;
         i += gridDim.x * blockDim.x) {
        float4 v = x[i];
        m = fminf(m, fminf(fminf(v.x, v.y), fminf(v.z, v.w)));
    }
    // wave-64 shuffle reduce
    #pragma unroll
    for (int off = 32; off > 0; off >>= 1)
        m = fminf(m, __shfl_down(m, off, 64));
    __shared__ float sm[4];
    int lane = threadIdx.x & 63, wid = threadIdx.x >> 6;
    if (lane == 0) sm[wid] = m;
    __syncthreads();
    if (threadIdx.x == 0) {
        float bm = sm[0];
        int nw = blockDim.x >> 6;
        for (int w = 1; w < nw; ++w) bm = fminf(bm, sm[w]);
        atomicMin(ws, enc_f32(bm));
    }
}

__device__ __forceinline__ float4 max4(float4 a, float4 b) {
    return make_float4(fmaxf(a.x, b.x), fmaxf(a.y, b.y),
                       fmaxf(a.z, b.z), fmaxf(a.w, b.w));
}

// One block per (b, w). 192 threads; thread t owns float4 slice t of D.
__global__ __launch_bounds__(192) void word_max(
    const float* __restrict__ emb, const int* __restrict__ p2w,
    const unsigned int* __restrict__ ws, float* __restrict__ out)
{
    const int bw = blockIdx.x;         // 0 .. B*Lw-1
    const int b = bw / LW_;
    const int w = bw - b * LW_;

    __shared__ int   active[LP_];
    __shared__ int   s_cnt;
    __shared__ float s_minv;
    if (threadIdx.x == 0) { s_cnt = 0; s_minv = dec_f32(ws[0]); }
    __syncthreads();

    // Compact mask row -> active piece index list (order irrelevant for max).
    const int* mrow = p2w + (b * LW_ + w) * LP_;
    for (int p = threadIdx.x; p < LP_; p += blockDim.x) {
        if (mrow[p] != 0) {
            int slot = atomicAdd(&s_cnt, 1);
            active[slot] = p;
        }
    }
    __syncthreads();

    const float  minv = s_minv;
    const int    n    = s_cnt;
    const int    dv   = threadIdx.x;            // 0..191
    const float4* erow = (const float4*)(emb + b * LP_ * D_);

    float4 acc = make_float4(minv, minv, minv, minv);

    int i = 0;
    for (; i + 4 <= n; i += 4) {
        int p0 = active[i + 0];
        int p1 = active[i + 1];
        int p2 = active[i + 2];
        int p3 = active[i + 3];
        float4 v0 = erow[p0 * D4_ + dv];
        float4 v1 = erow[p1 * D4_ + dv];
        float4 v2 = erow[p2 * D4_ + dv];
        float4 v3 = erow[p3 * D4_ + dv];
        acc = max4(acc, max4(max4(v0, v1), max4(v2, v3)));
    }
    for (; i < n; ++i) {
        acc = max4(acc, erow[active[i] * D4_ + dv]);
    }

    ((float4*)out)[(b * LW_ + w) * D4_ + dv] = acc;
}

extern "C" void kernel_launch(void* const* d_in, const int* in_sizes, int n_in,
                              void* d_out, int out_size, void* d_ws, size_t ws_size,
                              hipStream_t stream) {
    const float* emb = (const float*)d_in[0];
    const int*   p2w = (const int*)d_in[1];
    float*       out = (float*)d_out;
    unsigned int* ws = (unsigned int*)d_ws;

    init_ws<<<1, 64, 0, stream>>>(ws);

    const int n4 = (B_ * LP_ * D_) / 4;  // 196608
    min_reduce<<<256, 256, 0, stream>>>((const float4*)emb, n4, ws);

    word_max<<<B_ * LW_, 192, 0, stream>>>(emb, p2w, ws, out);
}

// Round 2
// 77.213 us; speedup vs baseline: 1.0135x; 1.0135x over previous
//
#include <hip/hip_runtime.h>
#include <hip/hip_bf16.h>

// Problem shape (fixed by reference setup_inputs):
//   bert_emb:    [B=4, Lp=256, D=768] fp32
//   pieces2word: [B=4, Lw=200, Lp=256] int32 (0/1)
//   out:         [B=4, Lw=200, D=768] fp32
// out[b,w,d] = max over {p : mask[b,w,p]!=0} of emb[b,p,d], else global min(emb).
//
// Design notes (R1):
//  - NO global atomics: kernel1 writes 64 per-block partial mins to ws;
//    kernel2 reduces those 64 floats per block (cheap, broadcast from L2).
//  - NO LDS atomics: mask compaction via __ballot + cross-wave prefix sum
//    (256 threads == Lp, so exactly one ballot round).
//  - Main loop: threads 0..191 each own one float4 of D; unroll-4 piece loop
//    keeps 4 dwordx4 loads in flight per thread. Wave 3 only helps compaction.

#define B_  4
#define LP_ 256
#define LW_ 200
#define D_  768
#define D4_ (D_ / 4)     // 192 float4 per row
#define NMIN_BLOCKS 64

// ---- Kernel 1: per-block partial min over emb (no atomics) ----
__global__ __launch_bounds__(256) void block_min(
    const float4* __restrict__ x, float* __restrict__ ws)
{
    const int n4 = (B_ * LP_ * D_) / 4;           // 196608
    float m = __uint_as_float(0x7F800000u);       // +inf
    for (int i = blockIdx.x * blockDim.x + threadIdx.x; i < n4;
         i += gridDim.x * blockDim.x) {
        float4 v = x[i];
        m = fminf(m, fminf(fminf(v.x, v.y), fminf(v.z, v.w)));
    }
    #pragma unroll
    for (int off = 32; off > 0; off >>= 1)
        m = fminf(m, __shfl_down(m, off, 64));
    __shared__ float sm[4];
    int lane = threadIdx.x & 63, wid = threadIdx.x >> 6;
    if (lane == 0) sm[wid] = m;
    __syncthreads();
    if (threadIdx.x == 0) {
        float bm = fminf(fminf(sm[0], sm[1]), fminf(sm[2], sm[3]));
        ws[blockIdx.x] = bm;
    }
}

__device__ __forceinline__ float4 max4(float4 a, float4 b) {
    return make_float4(fmaxf(a.x, b.x), fmaxf(a.y, b.y),
                       fmaxf(a.z, b.z), fmaxf(a.w, b.w));
}

// ---- Kernel 2: one block per (b, w); 256 threads (4 waves) ----
__global__ __launch_bounds__(256) void word_max(
    const float* __restrict__ emb, const int* __restrict__ p2w,
    const float* __restrict__ ws, float* __restrict__ out)
{
    const int bw = blockIdx.x;          // 0 .. B*Lw-1
    const int b = bw / LW_;
    const int w = bw - b * LW_;
    const int tid = threadIdx.x;
    const int lane = tid & 63, wid = tid >> 6;

    __shared__ int   active[LP_];
    __shared__ int   wcnt[4];
    __shared__ float s_minv;

    // Reduce the 64 partial mins (wave 0 only).
    if (wid == 0) {
        float m = ws[lane];
        #pragma unroll
        for (int off = 32; off > 0; off >>= 1)
            m = fminf(m, __shfl_down(m, off, 64));
        if (lane == 0) s_minv = m;
    }

    // Ballot compaction: thread tid owns piece p = tid (LP_ == 256).
    const int* mrow = p2w + (b * LW_ + w) * LP_;
    const bool act = (mrow[tid] != 0);
    const unsigned long long bal = __ballot(act);
    if (lane == 0) wcnt[wid] = __popcll(bal);
    __syncthreads();

    int off = 0;
    #pragma unroll
    for (int i = 0; i < 4; ++i) off += (i < wid) ? wcnt[i] : 0;
    if (act) {
        int pos = off + __popcll(bal & ((1ull << lane) - 1ull));
        active[pos] = tid;
    }
    const int n = wcnt[0] + wcnt[1] + wcnt[2] + wcnt[3];
    __syncthreads();

    if (tid >= D4_) return;             // wave 3 done (no output columns)

    const float  minv = s_minv;
    const float4* erow = (const float4*)(emb + b * LP_ * D_);
    float4 acc = make_float4(minv, minv, minv, minv);

    int i = 0;
    for (; i + 4 <= n; i += 4) {
        int p0 = active[i + 0];
        int p1 = active[i + 1];
        int p2 = active[i + 2];
        int p3 = active[i + 3];
        float4 v0 = erow[p0 * D4_ + tid];
        float4 v1 = erow[p1 * D4_ + tid];
        float4 v2 = erow[p2 * D4_ + tid];
        float4 v3 = erow[p3 * D4_ + tid];
        acc = max4(acc, max4(max4(v0, v1), max4(v2, v3)));
    }
    for (; i < n; ++i) {
        acc = max4(acc, erow[active[i] * D4_ + tid]);
    }

    ((float4*)out)[(b * LW_ + w) * D4_ + tid] = acc;
}

extern "C" void kernel_launch(void* const* d_in, const int* in_sizes, int n_in,
                              void* d_out, int out_size, void* d_ws, size_t ws_size,
                              hipStream_t stream) {
    const float* emb = (const float*)d_in[0];
    const int*   p2w = (const int*)d_in[1];
    float*       out = (float*)d_out;
    float*       ws  = (float*)d_ws;

    block_min<<<NMIN_BLOCKS, 256, 0, stream>>>((const float4*)emb, ws);
    word_max<<<B_ * LW_, 256, 0, stream>>>(emb, p2w, ws, out);
}

// Round 3
// 72.165 us; speedup vs baseline: 1.0844x; 1.0699x over previous
//
#include <hip/hip_runtime.h>

// Problem shape (fixed by reference setup_inputs):
//   bert_emb:    [B=4, Lp=256, D=768] fp32
//   pieces2word: [B=4, Lw=200, Lp=256] int32 (0/1)
//   out:         [B=4, Lw=200, D=768] fp32
// out[b,w,d] = max over {p : mask[b,w,p]!=0} of emb[b,p,d], else global min(emb).
//
// R2 design:
//  - SINGLE kernel, no workspace. The global-min pass is eliminated: the
//    max accumulator is initialized from the FIRST active row (bit-exact,
//    max is a selection). An all-zero mask row (needs global min) is
//    handled by a correct in-block fallback that is never taken for the
//    fixed random inputs (P = 2^-256 per row).
//  - 2400 one-wave (64-thread) blocks: (b, w) x 3 column-chunks of 64
//    float4. 9.4 blocks/CU -> negligible tail quantization (vs 3.125).
//  - One-wave block => in-wave ballot compaction, ZERO __syncthreads.
//  - Main loop: unroll-4 global_load_dwordx4 gathers, L2-resident emb.

#define B_  4
#define LP_ 256
#define LW_ 200
#define D_  768
#define D4_ (D_ / 4)            // 192 float4 per row
#define CHUNKS 3                // 3 chunks of 64 float4 columns
#define NBLK (B_ * LW_ * CHUNKS) // 2400 blocks

__device__ __forceinline__ float4 max4(float4 a, float4 b) {
    return make_float4(fmaxf(a.x, b.x), fmaxf(a.y, b.y),
                       fmaxf(a.z, b.z), fmaxf(a.w, b.w));
}

__global__ __launch_bounds__(64) void word_max(
    const float* __restrict__ emb, const int* __restrict__ p2w,
    float* __restrict__ out)
{
    const int blk   = blockIdx.x;
    const int chunk = blk % CHUNKS;
    const int bw    = blk / CHUNKS;        // 0 .. B*Lw-1
    const int b     = bw / LW_;
    const int w     = bw - b * LW_;
    const int lane  = threadIdx.x;         // 0..63

    // In-wave mask compaction: 4 ballot rounds (256 pieces / 64 lanes).
    __shared__ int active[LP_];
    const int* mrow = p2w + (b * LW_ + w) * LP_;
    int cnt = 0;
    #pragma unroll
    for (int r = 0; r < 4; ++r) {
        const bool a = (mrow[r * 64 + lane] != 0);
        const unsigned long long bal = __ballot(a);
        if (a) {
            int pos = cnt + __popcll(bal & ((1ull << lane) - 1ull));
            active[pos] = r * 64 + lane;
        }
        cnt += __popcll(bal);
    }
    // Same-wave LDS write->read: compiler inserts lgkmcnt wait; no barrier.

    const float4* erow = (const float4*)(emb + b * LP_ * D_) + chunk * 64 + lane;
    float4*       orow = (float4*)out + bw * D4_ + chunk * 64 + lane;

    if (cnt == 0) {
        // Never taken for the fixed inputs; correct fallback = global min
        // over ALL of emb (matches reference min_value semantics).
        const float4* x = (const float4*)emb;
        const int n4 = (B_ * LP_ * D_) / 4;
        float m = __uint_as_float(0x7F800000u);  // +inf
        for (int i = lane; i < n4; i += 64) {
            float4 v = x[i];
            m = fminf(m, fminf(fminf(v.x, v.y), fminf(v.z, v.w)));
        }
        #pragma unroll
        for (int off = 32; off > 0; off >>= 1)
            m = fminf(m, __shfl_down(m, off, 64));
        m = __shfl(m, 0, 64);
        *orow = make_float4(m, m, m, m);
        return;
    }

    // Init from first active row (no min needed), then unroll-4 gather-max.
    float4 acc = erow[active[0] * D4_];
    int i = 1;
    for (; i + 4 <= cnt; i += 4) {
        const int p0 = active[i + 0];
        const int p1 = active[i + 1];
        const int p2 = active[i + 2];
        const int p3 = active[i + 3];
        const float4 v0 = erow[p0 * D4_];
        const float4 v1 = erow[p1 * D4_];
        const float4 v2 = erow[p2 * D4_];
        const float4 v3 = erow[p3 * D4_];
        acc = max4(acc, max4(max4(v0, v1), max4(v2, v3)));
    }
    for (; i < cnt; ++i)
        acc = max4(acc, erow[active[i] * D4_]);

    *orow = acc;
}

extern "C" void kernel_launch(void* const* d_in, const int* in_sizes, int n_in,
                              void* d_out, int out_size, void* d_ws, size_t ws_size,
                              hipStream_t stream) {
    const float* emb = (const float*)d_in[0];
    const int*   p2w = (const int*)d_in[1];
    float*       out = (float*)d_out;
    (void)d_ws; (void)ws_size;

    word_max<<<NBLK, 64, 0, stream>>>(emb, p2w, out);
}

// Round 4
// 70.559 us; speedup vs baseline: 1.1091x; 1.0228x over previous
//
#include <hip/hip_runtime.h>

// Problem shape (fixed by reference setup_inputs):
//   bert_emb:    [B=4, Lp=256, D=768] fp32
//   pieces2word: [B=4, Lw=200, Lp=256] int32 (0/1)
//   out:         [B=4, Lw=200, D=768] fp32
// out[b,w,d] = max over {p : mask[b,w,p]!=0} of emb[b,p,d], else global min(emb).
//
// R3 design:
//  - Single kernel, no workspace, no global-min pass (acc init = -inf;
//    bit-exact since max is a selection and cnt>0 for the fixed inputs;
//    cnt==0 handled by a correct global-min fallback, never taken).
//  - 2400 blocks x 128 threads (2 waves): block = (b, w, 64-float4 chunk).
//    Wave k processes active rows k, k+2, k+4, ... -> 4.7 waves/SIMD,
//    ~150 KB of loads in flight per CU (>> BW-delay product) => L2-BW-bound.
//  - Mask compaction computed redundantly by BOTH waves (identical LDS
//    writes, benign race) => zero barriers before the hot loop.
//  - Hot loop: unroll-8 global_load_dwordx4 gathers (8 in flight/wave).
//  - End: wave1 -> LDS, one __syncthreads, wave0 merges + stores.

#define B_  4
#define LP_ 256
#define LW_ 200
#define D_  768
#define D4_ (D_ / 4)             // 192 float4 per row
#define CHUNKS 3                 // 3 chunks of 64 float4 columns
#define NBLK (B_ * LW_ * CHUNKS) // 2400 blocks

__device__ __forceinline__ float4 max4(float4 a, float4 b) {
    return make_float4(fmaxf(a.x, b.x), fmaxf(a.y, b.y),
                       fmaxf(a.z, b.z), fmaxf(a.w, b.w));
}

__global__ __launch_bounds__(128) void word_max(
    const float* __restrict__ emb, const int* __restrict__ p2w,
    float* __restrict__ out)
{
    const int blk   = blockIdx.x;
    const int chunk = blk % CHUNKS;
    const int bw    = blk / CHUNKS;        // 0 .. B*Lw-1
    const int b     = bw / LW_;
    const int w     = bw - b * LW_;
    const int lane  = threadIdx.x & 63;
    const int wv    = threadIdx.x >> 6;    // 0 or 1

    __shared__ int    active[LP_];
    __shared__ float4 sacc[64];

    // Redundant in-wave compaction (both waves compute identical results and
    // write identical values -> benign race, no barrier needed).
    const int* mrow = p2w + (b * LW_ + w) * LP_;
    int cnt = 0;
    #pragma unroll
    for (int r = 0; r < 4; ++r) {
        const bool a = (mrow[r * 64 + lane] != 0);
        const unsigned long long bal = __ballot(a);
        if (a) {
            int pos = cnt + __popcll(bal & ((1ull << lane) - 1ull));
            active[pos] = r * 64 + lane;
        }
        cnt += __popcll(bal);
    }

    const float4* erow = (const float4*)(emb + b * LP_ * D_) + chunk * 64 + lane;
    float4*       orow = (float4*)out + bw * D4_ + chunk * 64 + lane;

    if (cnt == 0) {
        // Never taken for the fixed inputs; correct fallback = global min
        // over ALL of emb (reference min_value semantics).
        if (wv == 0) {
            const float4* x = (const float4*)emb;
            const int n4 = (B_ * LP_ * D_) / 4;
            float m = __uint_as_float(0x7F800000u);  // +inf
            for (int i = lane; i < n4; i += 64) {
                float4 v = x[i];
                m = fminf(m, fminf(fminf(v.x, v.y), fminf(v.z, v.w)));
            }
            #pragma unroll
            for (int off = 32; off > 0; off >>= 1)
                m = fminf(m, __shfl_down(m, off, 64));
            m = __shfl(m, 0, 64);
            *orow = make_float4(m, m, m, m);
        }
        return;
    }

    const float ninf = __uint_as_float(0xFF800000u);  // -inf
    float4 acc = make_float4(ninf, ninf, ninf, ninf);

    // Wave wv owns active rows wv, wv+2, wv+4, ...  Unroll-8.
    int i = wv;
    while (i + 14 < cnt) {
        const int p0 = active[i +  0];
        const int p1 = active[i +  2];
        const int p2 = active[i +  4];
        const int p3 = active[i +  6];
        const int p4 = active[i +  8];
        const int p5 = active[i + 10];
        const int p6 = active[i + 12];
        const int p7 = active[i + 14];
        const float4 v0 = erow[p0 * D4_];
        const float4 v1 = erow[p1 * D4_];
        const float4 v2 = erow[p2 * D4_];
        const float4 v3 = erow[p3 * D4_];
        const float4 v4 = erow[p4 * D4_];
        const float4 v5 = erow[p5 * D4_];
        const float4 v6 = erow[p6 * D4_];
        const float4 v7 = erow[p7 * D4_];
        acc = max4(acc, max4(max4(max4(v0, v1), max4(v2, v3)),
                             max4(max4(v4, v5), max4(v6, v7))));
        i += 16;
    }
    for (; i < cnt; i += 2)
        acc = max4(acc, erow[active[i] * D4_]);

    // Merge the two waves' partials.
    if (wv == 1) sacc[lane] = acc;
    __syncthreads();
    if (wv == 0) {
        acc = max4(acc, sacc[lane]);
        *orow = acc;
    }
}

extern "C" void kernel_launch(void* const* d_in, const int* in_sizes, int n_in,
                              void* d_out, int out_size, void* d_ws, size_t ws_size,
                              hipStream_t stream) {
    const float* emb = (const float*)d_in[0];
    const int*   p2w = (const int*)d_in[1];
    float*       out = (float*)d_out;
    (void)d_ws; (void)ws_size;

    word_max<<<NBLK, 128, 0, stream>>>(emb, p2w, out);
}